// Round 2
// baseline (371.463 us; speedup 1.0000x reference)
//
#include <hip/hip_runtime.h>
#include <cstdint>

// Problem constants (B,N,H,D fixed by setup_inputs)
#define BB 2
#define NN 2048
#define HH 16
#define DD 128
#define BH 32   // BB*HH
#define NPROJ 7

typedef __bf16 bf16x8 __attribute__((ext_vector_type(8)));
typedef float f32x4 __attribute__((ext_vector_type(4)));

__device__ __forceinline__ unsigned short f2bf(float f) {
  unsigned int u = __float_as_uint(f);
  u += 0x7fff + ((u >> 16) & 1);   // RN-even
  return (unsigned short)(u >> 16);
}

__device__ __forceinline__ bf16x8 load_q8(const float* p) {
  float4 a = *(const float4*)p;
  float4 b = *(const float4*)(p + 4);
  unsigned short r[8] = {f2bf(a.x), f2bf(a.y), f2bf(a.z), f2bf(a.w),
                         f2bf(b.x), f2bf(b.y), f2bf(b.z), f2bf(b.w)};
  return *(bf16x8*)r;
}

// ---------------------------------------------------------------------------
// 1) Fused: LSH hash of q and k rows (blocks < 4096) + V bf16 transpose to
//    [B,H,D,N] (blocks >= 4096). Hash: 8 lanes per row, fp64 accumulation.
//    The k-hash path also emits K in bf16 [B,H,N,D] (Kb).  (unchanged)
// ---------------------------------------------------------------------------
__global__ void prep_kernel(const float* __restrict__ q, const float* __restrict__ k,
                            const float* __restrict__ v, const float* __restrict__ pd,
                            int* __restrict__ qh, int* __restrict__ kh,
                            unsigned short* __restrict__ Vt, unsigned short* __restrict__ Kb) {
  __shared__ __align__(16) char smem[64 * 132 * 2];  // union: spd (3.5K) / tile (16.5K)
  if (blockIdx.x < 4096) {
    float* spd = (float*)smem;
    for (int i = threadIdx.x; i < DD * NPROJ; i += 256) spd[i] = pd[i];
    __syncthreads();
    long long gid = (long long)blockIdx.x * 256 + threadIdx.x;
    int part = (int)(gid & 7);
    long long row = gid >> 3;
    const long long NR = (long long)BB * NN * HH;
    int isk = row >= NR;
    long long r = isk ? row - NR : row;            // flat [b][n][h]
    const float* src = (isk ? k : q) + r * DD + part * 16;
    double acc[NPROJ];
    for (int p = 0; p < NPROJ; ++p) acc[p] = 0.0;
    __align__(16) unsigned short kb16[16];
    for (int d = 0; d < 16; d += 4) {
      float4 x = *(const float4*)(src + d);
      if (isk) {
        kb16[d + 0] = f2bf(x.x); kb16[d + 1] = f2bf(x.y);
        kb16[d + 2] = f2bf(x.z); kb16[d + 3] = f2bf(x.w);
      }
      int dbase = part * 16 + d;
      for (int p = 0; p < NPROJ; ++p) {
        acc[p] += (double)x.x * (double)spd[(dbase + 0) * NPROJ + p]
                + (double)x.y * (double)spd[(dbase + 1) * NPROJ + p]
                + (double)x.z * (double)spd[(dbase + 2) * NPROJ + p]
                + (double)x.w * (double)spd[(dbase + 3) * NPROJ + p];
      }
    }
    int b_ = (int)(r / (NN * HH));
    int rem = (int)(r % (NN * HH));
    int n_ = rem / HH, h_ = rem % HH;
    if (isk) {
      unsigned short* dst = Kb + (((long long)(b_ * HH + h_) * NN + n_) << 7) + part * 16;
      *(uint4*)dst = *(const uint4*)&kb16[0];
      *(uint4*)(dst + 8) = *(const uint4*)&kb16[8];
    }
    for (int off = 1; off < 8; off <<= 1)
      for (int p = 0; p < NPROJ; ++p) acc[p] += __shfl_xor(acc[p], off);
    if (part == 0) {
      int bin = 0;
      for (int p = 0; p < NPROJ; ++p) bin |= ((int)(acc[p] > 0.0)) << p;
      int hsh = bin ^ (bin >> 1);                  // _unit_hamming == Gray code
      (isk ? kh : qh)[((long long)b_ * HH + h_) * NN + n_] = hsh;
    }
  } else {
    unsigned short (*tile)[132] = (unsigned short(*)[132])smem;
    int blk = blockIdx.x - 4096;
    int bh = blk >> 5;
    int n0 = (blk & 31) * 64;
    int b = bh >> 4, h = bh & 15;
    for (int it = 0; it < 8; ++it) {
      int cid = it * 256 + threadIdx.x;
      int r = cid >> 5, d4 = (cid & 31) * 4;
      float4 x = *(const float4*)(v + (((long long)(b * NN + n0 + r) * HH + h) << 7) + d4);
      *(ushort4*)&tile[r][d4] = make_ushort4(f2bf(x.x), f2bf(x.y), f2bf(x.z), f2bf(x.w));
    }
    __syncthreads();
    for (int it = 0; it < 8; ++it) {
      int cid = it * 256 + threadIdx.x;
      int d = cid >> 4, n4 = (cid & 15) * 4;
      ushort4 y = make_ushort4(tile[n4 + 0][d], tile[n4 + 1][d], tile[n4 + 2][d], tile[n4 + 3][d]);
      *(ushort4*)(Vt + ((long long)bh * DD + d) * NN + n0 + n4) = y;
    }
  }
}

// ---------------------------------------------------------------------------
// 2) Stable counting sort of q_hash per (b,h) + fused keep computation.
//    (unchanged)
// ---------------------------------------------------------------------------
__global__ void sortkeep_kernel(const int* __restrict__ qh, const int* __restrict__ kh,
                                int* __restrict__ sidx, int* __restrict__ keep) {
  __shared__ int sh[NN];
  __shared__ int cnt[4][128];
  __shared__ int cum[128];
  __shared__ int kflag[2];
  int bh = blockIdx.x;
  const int* src = qh + (long long)bh * NN;
  for (int i = threadIdx.x; i < NN; i += 512) sh[i] = src[i];
  if (threadIdx.x < 2) kflag[threadIdx.x] = 0;
  __syncthreads();
  int bin = threadIdx.x & 127, seg = threadIdx.x >> 7;
  int n0 = seg * (NN / 4);
  int c = 0;
  for (int n = n0; n < n0 + NN / 4; ++n) c += (sh[n] == bin);
  cnt[seg][bin] = c;
  __syncthreads();
  if (threadIdx.x == 0) {
    int run = 0;
    for (int t = 0; t < 128; ++t) {
      cum[t] = run;
      run += cnt[0][t] + cnt[1][t] + cnt[2][t] + cnt[3][t];
    }
  }
  __syncthreads();
  int pos = cum[bin];
  for (int s = 0; s < seg; ++s) pos += cnt[s][bin];
  int f0 = 0, f1 = 0;
  for (int n = n0; n < n0 + NN / 4; ++n)
    if (sh[n] == bin) {
      sidx[(long long)bh * NN + pos] = n;
      int match = (bin == kh[(long long)bh * NN + pos]);
      if (pos < 1024) f0 |= match; else f1 |= match;
      ++pos;
    }
  if (f0) atomicOr(&kflag[0], 1);
  if (f1) atomicOr(&kflag[1], 1);
  __syncthreads();
  if (threadIdx.x < 2) keep[bh * 2 + threadIdx.x] = kflag[threadIdx.x];
}

// ---------------------------------------------------------------------------
// 3) Flash attention over sorted Q, load-balanced TWO-PHASE blocks.
//    NEW vs previous round: each wave owns 32 q-rows (two 16-row groups A/B)
//    so every kf/vf LDS fragment read feeds TWO MFMAs -> per-FLOP LDS read
//    traffic (the measured bottleneck) halves. Block q-tile = 128 rows,
//    grid (8,32) = 256 blocks, 1 block/CU. Two-phase pairing keeps all
//    blocks at exactly 34 k-iterations. Double-buffered K/V staging with
//    early register prefetch (unchanged macros), Pb doubled to 32 rows/wave.
//    LDS: 2*17408 (Kt) + 2*18432 (Vs) + 18432 (Pb) = 90112 B = 88 KiB.
// ---------------------------------------------------------------------------
__global__ __launch_bounds__(256, 1)
void flash_kernel(const float* __restrict__ q, const unsigned short* __restrict__ Kb,
                  const unsigned short* __restrict__ Vt, const int* __restrict__ sidx,
                  const int* __restrict__ keep, float* __restrict__ out) {
  __shared__ __align__(16) unsigned short Kt[2][64 * 136];   // keys x d (+8 pad)
  __shared__ __align__(16) unsigned short Vs[2][128 * 72];   // d x keys (+8 pad)
  __shared__ __align__(16) unsigned short Pb[4][32 * 72];    // per-wave 32q x keys

  int bx = blockIdx.x;              // 0..7
  int bh = blockIdx.y;
  int b = bh >> 4, h = bh & 15;
  int tid = threadIdx.x;
  int w = tid >> 6, lane = tid & 63;
  int l16 = lane & 15, qd = lane >> 4;

  const unsigned short* Kh = Kb + (long long)bh * NN * DD;
  const unsigned short* Vb = Vt + (long long)bh * DD * NN;
  const float scale = 0.088388347648318447f;  // 128^-0.5

  // staging geometry (unchanged): K tile 64x128 bf16, V tile 128x64 bf16
  const int ksr = tid >> 4;          // K row base (+ it*16)
  const int ksc = (tid & 15) * 8;    // K col (ushort units)
  const int vsr = tid >> 3;          // V row base (+ it*32)
  const int vsc = (tid & 7) * 8;     // V col (ushort units)

  uint4 kreg[4], vreg[4];

#define STAGE_LOAD(K0, KP)                                                            \
  {                                                                                   \
    if (KP) {                                                                         \
      _Pragma("unroll")                                                               \
      for (int it = 0; it < 4; ++it)                                                  \
        kreg[it] = *(const uint4*)(Kh + (long long)((K0) + it * 16 + ksr) * DD + ksc);\
    } else {                                                                          \
      _Pragma("unroll")                                                               \
      for (int it = 0; it < 4; ++it) kreg[it] = make_uint4(0, 0, 0, 0);               \
    }                                                                                 \
    _Pragma("unroll")                                                                 \
    for (int it = 0; it < 4; ++it)                                                    \
      vreg[it] = *(const uint4*)(Vb + (long long)(it * 32 + vsr) * NN + (K0) + vsc);  \
  }

#define STAGE_WRITE(BUF)                                                              \
  {                                                                                   \
    _Pragma("unroll")                                                                 \
    for (int it = 0; it < 4; ++it)                                                    \
      *(uint4*)&Kt[BUF][(it * 16 + ksr) * 136 + ksc] = kreg[it];                      \
    _Pragma("unroll")                                                                 \
    for (int it = 0; it < 4; ++it)                                                    \
      *(uint4*)&Vs[BUF][(it * 32 + vsr) * 72 + vsc] = vreg[it];                       \
  }

  for (int ph = 0; ph < 2; ++ph) {
    int QT = ph ? bx : 15 - bx;     // heavy 128-row tile first (QT in 0..15)
    int qrowA = QT * 128 + w * 32 + l16;
    int qrowB = qrowA + 16;

    // Q fragments for both groups, gathered from fp32 q via sidx
    bf16x8 qfA[4], qfB[4];
    {
      int nqA = sidx[bh * NN + qrowA];
      int nqB = sidx[bh * NN + qrowB];
      const float* pA = q + (((long long)(b * NN + nqA) * HH + h) << 7) + qd * 8;
      const float* pB = q + (((long long)(b * NN + nqB) * HH + h) << 7) + qd * 8;
#pragma unroll
      for (int c = 0; c < 4; ++c) {
        qfA[c] = load_q8(pA + c * 32);
        qfB[c] = load_q8(pB + c * 32);
      }
    }
    f32x4 oA[8], oB[8];
#pragma unroll
    for (int i = 0; i < 8; ++i) {
      oA[i] = (f32x4){0.f, 0.f, 0.f, 0.f};
      oB[i] = (f32x4){0.f, 0.f, 0.f, 0.f};
    }
    float mA = -__builtin_inff(), lA = 0.f;
    float mB = -__builtin_inff(), lB = 0.f;

    int NKB = 2 * QT + 2;           // 64-key tiles needed for this q-tile

    // prologue: stage tile 0 into buffer 0
    int cur = 0;
    STAGE_LOAD(0, keep[h * 4]);
    __syncthreads();                 // previous phase's LDS readers are done
    STAGE_WRITE(0);
    __syncthreads();

    for (int kb = 0; kb < NKB; ++kb) {
      // issue next tile's global loads BEFORE compute (latency hides here)
      if (kb + 1 < NKB) STAGE_LOAD((kb + 1) * 64, keep[h * 4 + ((kb + 1) >> 3)]);

      int k0 = kb * 64;
      const unsigned short* Ktc = Kt[cur];
      const unsigned short* Vsc = Vs[cur];

      // --- S^T = K * Q^T for both q-groups (each kf read feeds 2 MFMAs) ---
      float sA[16], sB[16];
#pragma unroll
      for (int t = 0; t < 4; ++t) {
        f32x4 aA = (f32x4){0.f, 0.f, 0.f, 0.f};
        f32x4 aB = (f32x4){0.f, 0.f, 0.f, 0.f};
#pragma unroll
        for (int c = 0; c < 4; ++c) {
          bf16x8 kf = *(const bf16x8*)&Ktc[(t * 16 + l16) * 136 + c * 32 + qd * 8];
          aA = __builtin_amdgcn_mfma_f32_16x16x32_bf16(kf, qfA[c], aA, 0, 0, 0);
          aB = __builtin_amdgcn_mfma_f32_16x16x32_bf16(kf, qfB[c], aB, 0, 0, 0);
        }
        if (kb >= 2 * QT) {          // causal mask only near the diagonal
#pragma unroll
          for (int r = 0; r < 4; ++r) {
            int keyg = k0 + t * 16 + qd * 4 + r;
            sA[t * 4 + r] = (keyg > qrowA) ? -__builtin_inff() : aA[r] * scale;
            sB[t * 4 + r] = (keyg > qrowB) ? -__builtin_inff() : aB[r] * scale;
          }
        } else {
#pragma unroll
          for (int r = 0; r < 4; ++r) {
            sA[t * 4 + r] = aA[r] * scale;
            sB[t * 4 + r] = aB[r] * scale;
          }
        }
      }

      // --- online softmax, group A (stats per q = lane&15, replicated) ---
      {
        float mloc = sA[0];
#pragma unroll
        for (int i = 1; i < 16; ++i) mloc = fmaxf(mloc, sA[i]);
        mloc = fmaxf(mloc, __shfl_xor(mloc, 16));
        mloc = fmaxf(mloc, __shfl_xor(mloc, 32));
        if (__any(mloc > mA)) {      // alpha==1 exactly when skipped
          float mnew = fmaxf(mA, mloc);
          float alpha = __expf(mA - mnew);
          float aO[4];
#pragma unroll
          for (int r = 0; r < 4; ++r) aO[r] = __shfl(alpha, qd * 4 + r);
#pragma unroll
          for (int c8 = 0; c8 < 8; ++c8)
#pragma unroll
            for (int r = 0; r < 4; ++r) oA[c8][r] *= aO[r];
          lA *= alpha;
          mA = mnew;
        }
        float psum = 0.f;
#pragma unroll
        for (int t = 0; t < 4; ++t) {
          float p0 = __expf(sA[t * 4 + 0] - mA);
          float p1 = __expf(sA[t * 4 + 1] - mA);
          float p2 = __expf(sA[t * 4 + 2] - mA);
          float p3 = __expf(sA[t * 4 + 3] - mA);
          psum += (p0 + p1) + (p2 + p3);
          *(ushort4*)&Pb[w][l16 * 72 + t * 16 + qd * 4] =
              make_ushort4(f2bf(p0), f2bf(p1), f2bf(p2), f2bf(p3));
        }
        psum += __shfl_xor(psum, 16);
        psum += __shfl_xor(psum, 32);
        lA += psum;
      }
      // --- online softmax, group B ---
      {
        float mloc = sB[0];
#pragma unroll
        for (int i = 1; i < 16; ++i) mloc = fmaxf(mloc, sB[i]);
        mloc = fmaxf(mloc, __shfl_xor(mloc, 16));
        mloc = fmaxf(mloc, __shfl_xor(mloc, 32));
        if (__any(mloc > mB)) {
          float mnew = fmaxf(mB, mloc);
          float alpha = __expf(mB - mnew);
          float aO[4];
#pragma unroll
          for (int r = 0; r < 4; ++r) aO[r] = __shfl(alpha, qd * 4 + r);
#pragma unroll
          for (int c8 = 0; c8 < 8; ++c8)
#pragma unroll
            for (int r = 0; r < 4; ++r) oB[c8][r] *= aO[r];
          lB *= alpha;
          mB = mnew;
        }
        float psum = 0.f;
#pragma unroll
        for (int t = 0; t < 4; ++t) {
          float p0 = __expf(sB[t * 4 + 0] - mB);
          float p1 = __expf(sB[t * 4 + 1] - mB);
          float p2 = __expf(sB[t * 4 + 2] - mB);
          float p3 = __expf(sB[t * 4 + 3] - mB);
          psum += (p0 + p1) + (p2 + p3);
          *(ushort4*)&Pb[w][(16 + l16) * 72 + t * 16 + qd * 4] =
              make_ushort4(f2bf(p0), f2bf(p1), f2bf(p2), f2bf(p3));
        }
        psum += __shfl_xor(psum, 16);
        psum += __shfl_xor(psum, 32);
        lB += psum;
      }

      // --- O += P * V  (each vf read feeds 2 MFMAs) ---
#pragma unroll
      for (int g = 0; g < 2; ++g) {
        bf16x8 pfA = *(const bf16x8*)&Pb[w][l16 * 72 + g * 32 + qd * 8];
        bf16x8 pfB = *(const bf16x8*)&Pb[w][(16 + l16) * 72 + g * 32 + qd * 8];
#pragma unroll
        for (int c8 = 0; c8 < 8; ++c8) {
          bf16x8 vf = *(const bf16x8*)&Vsc[(c8 * 16 + l16) * 72 + g * 32 + qd * 8];
          oA[c8] = __builtin_amdgcn_mfma_f32_16x16x32_bf16(pfA, vf, oA[c8], 0, 0, 0);
          oB[c8] = __builtin_amdgcn_mfma_f32_16x16x32_bf16(pfB, vf, oB[c8], 0, 0, 0);
        }
      }

      // write next tile to the other buffer; one barrier per iteration
      if (kb + 1 < NKB) {
        STAGE_WRITE(cur ^ 1);
        __syncthreads();
        cur ^= 1;
      }
    }

    // --- epilogue: normalize and scatter-unsort (no LDS access) ---
#pragma unroll
    for (int grp = 0; grp < 2; ++grp) {
      float lg = grp ? lB : lA;
      float lO[4];
      int nO[4];
#pragma unroll
      for (int r = 0; r < 4; ++r) {
        lO[r] = __shfl(lg, qd * 4 + r);
        nO[r] = sidx[(long long)bh * NN + QT * 128 + w * 32 + grp * 16 + qd * 4 + r];
      }
#pragma unroll
      for (int r = 0; r < 4; ++r) {
        float inv = 1.f / lO[r];
        float* ob = out + (((long long)(b * NN + nO[r]) * HH + h) << 7) + l16;
#pragma unroll
        for (int c8 = 0; c8 < 8; ++c8)
          ob[c8 * 16] = (grp ? oB : oA)[c8][r] * inv;
      }
    }
  }
#undef STAGE_LOAD
#undef STAGE_WRITE
}

// ---------------------------------------------------------------------------
// Workspace layout (bytes):
//   0        : q_hash   [B,H,N] int   (256 KiB)
//   256 KiB  : k_hash                 (256 KiB)
//   512 KiB  : sort_idx               (256 KiB)
//   768 KiB  : keep[64] int
//   2 MiB    : Vt bf16 [B,H,D,N]      (16 MiB)
//   18 MiB   : Kb bf16 [B,H,N,D]      (16 MiB)   total 34 MiB
// ---------------------------------------------------------------------------
extern "C" void kernel_launch(void* const* d_in, const int* in_sizes, int n_in,
                              void* d_out, int out_size, void* d_ws, size_t ws_size,
                              hipStream_t stream) {
  const float* q = (const float*)d_in[0];
  const float* k = (const float*)d_in[1];
  const float* v = (const float*)d_in[2];
  const float* pd = (const float*)d_in[3];
  float* out = (float*)d_out;
  char* ws = (char*)d_ws;
  int* qh   = (int*)(ws + 0);
  int* kh   = (int*)(ws + (1u << 18));
  int* sidx = (int*)(ws + (2u << 18));
  int* keep = (int*)(ws + 3u * (1u << 18));
  unsigned short* Vt = (unsigned short*)(ws + (2u << 20));
  unsigned short* Kb = (unsigned short*)(ws + (18u << 20));

  prep_kernel<<<5120, 256, 0, stream>>>(q, k, v, pd, qh, kh, Vt, Kb);
  sortkeep_kernel<<<32, 512, 0, stream>>>(qh, kh, sidx, keep);
  flash_kernel<<<dim3(8, 32), 256, 0, stream>>>(q, Kb, Vt, sidx, keep, out);
}

// Round 3
// 366.106 us; speedup vs baseline: 1.0146x; 1.0146x over previous
//
#include <hip/hip_runtime.h>
#include <cstdint>

// Problem constants (B,N,H,D fixed by setup_inputs)
#define BB 2
#define NN 2048
#define HH 16
#define DD 128
#define BH 32   // BB*HH
#define NPROJ 7

typedef __bf16 bf16x8 __attribute__((ext_vector_type(8)));
typedef float f32x4 __attribute__((ext_vector_type(4)));

__device__ __forceinline__ unsigned short f2bf(float f) {
  unsigned int u = __float_as_uint(f);
  u += 0x7fff + ((u >> 16) & 1);   // RN-even
  return (unsigned short)(u >> 16);
}

__device__ __forceinline__ bf16x8 load_q8(const float* p) {
  float4 a = *(const float4*)p;
  float4 b = *(const float4*)(p + 4);
  unsigned short r[8] = {f2bf(a.x), f2bf(a.y), f2bf(a.z), f2bf(a.w),
                         f2bf(b.x), f2bf(b.y), f2bf(b.z), f2bf(b.w)};
  return *(bf16x8*)r;
}

// ---------------------------------------------------------------------------
// 1) Fused: LSH hash of q and k rows (blocks < 4096) + V bf16 transpose to
//    [B,H,D,N] (blocks >= 4096). Hash: 8 lanes per row, fp64 accumulation.
//    The k-hash path also emits K in bf16 [B,H,N,D] (Kb).  (unchanged)
// ---------------------------------------------------------------------------
__global__ void prep_kernel(const float* __restrict__ q, const float* __restrict__ k,
                            const float* __restrict__ v, const float* __restrict__ pd,
                            int* __restrict__ qh, int* __restrict__ kh,
                            unsigned short* __restrict__ Vt, unsigned short* __restrict__ Kb) {
  __shared__ __align__(16) char smem[64 * 132 * 2];  // union: spd (3.5K) / tile (16.5K)
  if (blockIdx.x < 4096) {
    float* spd = (float*)smem;
    for (int i = threadIdx.x; i < DD * NPROJ; i += 256) spd[i] = pd[i];
    __syncthreads();
    long long gid = (long long)blockIdx.x * 256 + threadIdx.x;
    int part = (int)(gid & 7);
    long long row = gid >> 3;
    const long long NR = (long long)BB * NN * HH;
    int isk = row >= NR;
    long long r = isk ? row - NR : row;            // flat [b][n][h]
    const float* src = (isk ? k : q) + r * DD + part * 16;
    double acc[NPROJ];
    for (int p = 0; p < NPROJ; ++p) acc[p] = 0.0;
    __align__(16) unsigned short kb16[16];
    for (int d = 0; d < 16; d += 4) {
      float4 x = *(const float4*)(src + d);
      if (isk) {
        kb16[d + 0] = f2bf(x.x); kb16[d + 1] = f2bf(x.y);
        kb16[d + 2] = f2bf(x.z); kb16[d + 3] = f2bf(x.w);
      }
      int dbase = part * 16 + d;
      for (int p = 0; p < NPROJ; ++p) {
        acc[p] += (double)x.x * (double)spd[(dbase + 0) * NPROJ + p]
                + (double)x.y * (double)spd[(dbase + 1) * NPROJ + p]
                + (double)x.z * (double)spd[(dbase + 2) * NPROJ + p]
                + (double)x.w * (double)spd[(dbase + 3) * NPROJ + p];
      }
    }
    int b_ = (int)(r / (NN * HH));
    int rem = (int)(r % (NN * HH));
    int n_ = rem / HH, h_ = rem % HH;
    if (isk) {
      unsigned short* dst = Kb + (((long long)(b_ * HH + h_) * NN + n_) << 7) + part * 16;
      *(uint4*)dst = *(const uint4*)&kb16[0];
      *(uint4*)(dst + 8) = *(const uint4*)&kb16[8];
    }
    for (int off = 1; off < 8; off <<= 1)
      for (int p = 0; p < NPROJ; ++p) acc[p] += __shfl_xor(acc[p], off);
    if (part == 0) {
      int bin = 0;
      for (int p = 0; p < NPROJ; ++p) bin |= ((int)(acc[p] > 0.0)) << p;
      int hsh = bin ^ (bin >> 1);                  // _unit_hamming == Gray code
      (isk ? kh : qh)[((long long)b_ * HH + h_) * NN + n_] = hsh;
    }
  } else {
    unsigned short (*tile)[132] = (unsigned short(*)[132])smem;
    int blk = blockIdx.x - 4096;
    int bh = blk >> 5;
    int n0 = (blk & 31) * 64;
    int b = bh >> 4, h = bh & 15;
    for (int it = 0; it < 8; ++it) {
      int cid = it * 256 + threadIdx.x;
      int r = cid >> 5, d4 = (cid & 31) * 4;
      float4 x = *(const float4*)(v + (((long long)(b * NN + n0 + r) * HH + h) << 7) + d4);
      *(ushort4*)&tile[r][d4] = make_ushort4(f2bf(x.x), f2bf(x.y), f2bf(x.z), f2bf(x.w));
    }
    __syncthreads();
    for (int it = 0; it < 8; ++it) {
      int cid = it * 256 + threadIdx.x;
      int d = cid >> 4, n4 = (cid & 15) * 4;
      ushort4 y = make_ushort4(tile[n4 + 0][d], tile[n4 + 1][d], tile[n4 + 2][d], tile[n4 + 3][d]);
      *(ushort4*)(Vt + ((long long)bh * DD + d) * NN + n0 + n4) = y;
    }
  }
}

// ---------------------------------------------------------------------------
// 2) Stable counting sort of q_hash per (b,h) + fused keep computation.
//    (unchanged)
// ---------------------------------------------------------------------------
__global__ void sortkeep_kernel(const int* __restrict__ qh, const int* __restrict__ kh,
                                int* __restrict__ sidx, int* __restrict__ keep) {
  __shared__ int sh[NN];
  __shared__ int cnt[4][128];
  __shared__ int cum[128];
  __shared__ int kflag[2];
  int bh = blockIdx.x;
  const int* src = qh + (long long)bh * NN;
  for (int i = threadIdx.x; i < NN; i += 512) sh[i] = src[i];
  if (threadIdx.x < 2) kflag[threadIdx.x] = 0;
  __syncthreads();
  int bin = threadIdx.x & 127, seg = threadIdx.x >> 7;
  int n0 = seg * (NN / 4);
  int c = 0;
  for (int n = n0; n < n0 + NN / 4; ++n) c += (sh[n] == bin);
  cnt[seg][bin] = c;
  __syncthreads();
  if (threadIdx.x == 0) {
    int run = 0;
    for (int t = 0; t < 128; ++t) {
      cum[t] = run;
      run += cnt[0][t] + cnt[1][t] + cnt[2][t] + cnt[3][t];
    }
  }
  __syncthreads();
  int pos = cum[bin];
  for (int s = 0; s < seg; ++s) pos += cnt[s][bin];
  int f0 = 0, f1 = 0;
  for (int n = n0; n < n0 + NN / 4; ++n)
    if (sh[n] == bin) {
      sidx[(long long)bh * NN + pos] = n;
      int match = (bin == kh[(long long)bh * NN + pos]);
      if (pos < 1024) f0 |= match; else f1 |= match;
      ++pos;
    }
  if (f0) atomicOr(&kflag[0], 1);
  if (f1) atomicOr(&kflag[1], 1);
  __syncthreads();
  if (threadIdx.x < 2) keep[bh * 2 + threadIdx.x] = kflag[threadIdx.x];
}

// ---------------------------------------------------------------------------
// 3) Flash attention over sorted Q, load-balanced TWO-PHASE blocks.
//    Round-1 geometry (16 q/wave, 64-row tile, grid 16x32, 2 blocks/CU)
//    + NEW: 2-deep software pipeline inside the wave. Each barrier interval:
//        STAGE_WRITE(tile k+1); [softmax(S_k)  ||  QK(tile k+1) -> S_next];
//        PV(tile k)
//    so the serial softmax chain (fmax tree + shuffles + exp + Pb round-trip)
//    overlaps the 16 QK MFMAs of the next tile (different pipes). S-state is
//    double-buffered in statically-named regs s0/s1 (manual 2-unroll; no
//    runtime-indexed reg arrays -> no scratch). Pairwise fmax tree.
//    LDS: 2*17408 (Kt) + 2*18432 (Vs) + 9216 (Pb) = 80896 B; 2 blocks/CU.
// ---------------------------------------------------------------------------
__global__ __launch_bounds__(256, 2)
void flash_kernel(const float* __restrict__ q, const unsigned short* __restrict__ Kb,
                  const unsigned short* __restrict__ Vt, const int* __restrict__ sidx,
                  const int* __restrict__ keep, float* __restrict__ out) {
  __shared__ __align__(16) unsigned short Kt[2][64 * 136];   // keys x d (+8 pad)
  __shared__ __align__(16) unsigned short Vs[2][128 * 72];   // d x keys (+8 pad)
  __shared__ __align__(16) unsigned short Pb[4][16 * 72];    // per-wave q x keys

  int bx = blockIdx.x;              // 0..15
  int bh = blockIdx.y;
  int b = bh >> 4, h = bh & 15;
  int tid = threadIdx.x;
  int w = tid >> 6, lane = tid & 63;
  int l16 = lane & 15, qd = lane >> 4;

  const unsigned short* Kh = Kb + (long long)bh * NN * DD;
  const unsigned short* Vb = Vt + (long long)bh * DD * NN;
  const float scale = 0.088388347648318447f;  // 128^-0.5

  // staging geometry: K tile 64x128 bf16, V tile 128x64 bf16
  const int ksr = tid >> 4;          // K row base (+ it*16)
  const int ksc = (tid & 15) * 8;    // K col (ushort units)
  const int vsr = tid >> 3;          // V row base (+ it*32)
  const int vsc = (tid & 7) * 8;     // V col (ushort units)

  uint4 kreg[4], vreg[4];

#define STAGE_LOAD(K0, KP)                                                            \
  {                                                                                   \
    if (KP) {                                                                         \
      _Pragma("unroll")                                                               \
      for (int it = 0; it < 4; ++it)                                                  \
        kreg[it] = *(const uint4*)(Kh + (long long)((K0) + it * 16 + ksr) * DD + ksc);\
    } else {                                                                          \
      _Pragma("unroll")                                                               \
      for (int it = 0; it < 4; ++it) kreg[it] = make_uint4(0, 0, 0, 0);               \
    }                                                                                 \
    _Pragma("unroll")                                                                 \
    for (int it = 0; it < 4; ++it)                                                    \
      vreg[it] = *(const uint4*)(Vb + (long long)(it * 32 + vsr) * NN + (K0) + vsc);  \
  }

#define STAGE_WRITE(BUF)                                                              \
  {                                                                                   \
    _Pragma("unroll")                                                                 \
    for (int it = 0; it < 4; ++it)                                                    \
      *(uint4*)&Kt[BUF][(it * 16 + ksr) * 136 + ksc] = kreg[it];                      \
    _Pragma("unroll")                                                                 \
    for (int it = 0; it < 4; ++it)                                                    \
      *(uint4*)&Vs[BUF][(it * 32 + vsr) * 72 + vsc] = vreg[it];                       \
  }

// QK of tile T from LDS buf (T&1) into statically-named S[16]; mask on diagonal.
#define QK_TILE(T, S)                                                                 \
  {                                                                                   \
    const unsigned short* Ktc_ = Kt[(T) & 1];                                         \
    int k0_ = (T) * 64;                                                               \
    _Pragma("unroll")                                                                 \
    for (int t = 0; t < 4; ++t) {                                                     \
      f32x4 a1 = (f32x4){0.f, 0.f, 0.f, 0.f};                                         \
      _Pragma("unroll")                                                               \
      for (int c = 0; c < 4; ++c) {                                                   \
        bf16x8 kf = *(const bf16x8*)&Ktc_[(t * 16 + l16) * 136 + c * 32 + qd * 8];    \
        a1 = __builtin_amdgcn_mfma_f32_16x16x32_bf16(kf, qf[c], a1, 0, 0, 0);         \
      }                                                                               \
      if ((T) == qt) {                                                                \
        _Pragma("unroll")                                                             \
        for (int r = 0; r < 4; ++r) {                                                 \
          int keyg = k0_ + t * 16 + qd * 4 + r;                                       \
          (S)[t * 4 + r] = (keyg > qrow) ? -__builtin_inff() : a1[r] * scale;         \
        }                                                                             \
      } else {                                                                        \
        _Pragma("unroll")                                                             \
        for (int r = 0; r < 4; ++r) (S)[t * 4 + r] = a1[r] * scale;                   \
      }                                                                               \
    }                                                                                 \
  }

// Online-softmax update on S; writes P (bf16) to Pb[w]; updates m, l, rescales o.
#define SOFTMAX_UPDATE(S)                                                             \
  {                                                                                   \
    float x0_ = fmaxf(fmaxf((S)[0], (S)[1]), fmaxf((S)[2], (S)[3]));                  \
    float x1_ = fmaxf(fmaxf((S)[4], (S)[5]), fmaxf((S)[6], (S)[7]));                  \
    float x2_ = fmaxf(fmaxf((S)[8], (S)[9]), fmaxf((S)[10], (S)[11]));                \
    float x3_ = fmaxf(fmaxf((S)[12], (S)[13]), fmaxf((S)[14], (S)[15]));              \
    float mloc = fmaxf(fmaxf(x0_, x1_), fmaxf(x2_, x3_));                             \
    mloc = fmaxf(mloc, __shfl_xor(mloc, 16));                                         \
    mloc = fmaxf(mloc, __shfl_xor(mloc, 32));                                         \
    if (__any(mloc > m)) {      /* alpha==1 exactly when skipped */                   \
      float mnew = fmaxf(m, mloc);                                                    \
      float alpha = __expf(m - mnew);                                                 \
      float aO[4];                                                                    \
      _Pragma("unroll")                                                               \
      for (int r = 0; r < 4; ++r) aO[r] = __shfl(alpha, qd * 4 + r);                  \
      _Pragma("unroll")                                                               \
      for (int c8 = 0; c8 < 8; ++c8)                                                  \
        _Pragma("unroll")                                                             \
        for (int r = 0; r < 4; ++r) o[c8][r] *= aO[r];                                \
      l *= alpha;                                                                     \
      m = mnew;                                                                       \
    }                                                                                 \
    float psum = 0.f;                                                                 \
    _Pragma("unroll")                                                                 \
    for (int t = 0; t < 4; ++t) {                                                     \
      float p0 = __expf((S)[t * 4 + 0] - m);                                          \
      float p1 = __expf((S)[t * 4 + 1] - m);                                          \
      float p2 = __expf((S)[t * 4 + 2] - m);                                          \
      float p3 = __expf((S)[t * 4 + 3] - m);                                          \
      psum += (p0 + p1) + (p2 + p3);                                                  \
      *(ushort4*)&Pb[w][l16 * 72 + t * 16 + qd * 4] =                                 \
          make_ushort4(f2bf(p0), f2bf(p1), f2bf(p2), f2bf(p3));                       \
    }                                                                                 \
    psum += __shfl_xor(psum, 16);                                                     \
    psum += __shfl_xor(psum, 32);                                                     \
    l += psum;                                                                        \
  }

// O += P * V from LDS buf BUF (V fragments).
#define PV_ACC(BUF)                                                                   \
  {                                                                                   \
    const unsigned short* Vsc_ = Vs[BUF];                                             \
    _Pragma("unroll")                                                                 \
    for (int g = 0; g < 2; ++g) {                                                     \
      bf16x8 pf = *(const bf16x8*)&Pb[w][l16 * 72 + g * 32 + qd * 8];                 \
      _Pragma("unroll")                                                               \
      for (int c8 = 0; c8 < 8; ++c8) {                                                \
        bf16x8 vf = *(const bf16x8*)&Vsc_[(c8 * 16 + l16) * 72 + g * 32 + qd * 8];    \
        o[c8] = __builtin_amdgcn_mfma_f32_16x16x32_bf16(pf, vf, o[c8], 0, 0, 0);      \
      }                                                                               \
    }                                                                                 \
  }

// One pipeline step for tile KB: stage tile KB+1 into LDS (+ prefetch KB+2),
// then softmax of S(KB) overlapped with QK of tile KB+1, then PV of KB.
#define STEP(KB, SC, SN)                                                              \
  {                                                                                   \
    int nxt_ = (KB) + 1;                                                              \
    if (nxt_ <= qt) {                                                                 \
      __syncthreads();                /* prior PV/QK reads of buf nxt&1 done */       \
      STAGE_WRITE(nxt_ & 1);                                                          \
      __syncthreads();                /* writes visible to all waves */               \
      if (nxt_ + 1 <= qt) STAGE_LOAD((nxt_ + 1) * 64, keep[h * 4 + ((nxt_ + 1) >> 3)]); \
    }                                                                                 \
    SOFTMAX_UPDATE(SC);                                                               \
    if (nxt_ <= qt) QK_TILE(nxt_, SN);                                                \
    PV_ACC((KB) & 1);                                                                 \
  }

  for (int ph = 0; ph < 2; ++ph) {
    int qt = ph ? bx : 31 - bx;     // heavy tile first (qt in 0..31)
    int qrow = qt * 64 + w * 16 + l16;

    // Q fragments, gathered from fp32 q via sidx (once per phase)
    bf16x8 qf[4];
    {
      int nq = sidx[bh * NN + qrow];
      const float* p0 = q + (((long long)(b * NN + nq) * HH + h) << 7) + qd * 8;
#pragma unroll
      for (int c = 0; c < 4; ++c) qf[c] = load_q8(p0 + c * 32);
    }
    f32x4 o[8];
#pragma unroll
    for (int i = 0; i < 8; ++i) o[i] = (f32x4){0.f, 0.f, 0.f, 0.f};
    float m = -__builtin_inff(), l = 0.f;

    // prologue: stage tile 0, prefetch tile 1, compute S(0)
    STAGE_LOAD(0, keep[h * 4]);
    __syncthreads();                 // previous phase's LDS readers are done
    STAGE_WRITE(0);
    __syncthreads();
    if (qt > 0) STAGE_LOAD(64, keep[h * 4]);   // tile 1 (quarter 0)

    float s0[16], s1[16];
    QK_TILE(0, s0);

    int kb = 0;
    while (true) {
      STEP(kb, s0, s1); ++kb; if (kb > qt) break;
      STEP(kb, s1, s0); ++kb; if (kb > qt) break;
    }

    // --- epilogue: normalize and scatter-unsort (no LDS access) ---
    float lO[4];
    int nO[4];
#pragma unroll
    for (int r = 0; r < 4; ++r) {
      lO[r] = __shfl(l, qd * 4 + r);
      nO[r] = sidx[(long long)bh * NN + qt * 64 + w * 16 + qd * 4 + r];
    }
#pragma unroll
    for (int r = 0; r < 4; ++r) {
      float inv = 1.f / lO[r];
      float* ob = out + (((long long)(b * NN + nO[r]) * HH + h) << 7) + l16;
#pragma unroll
      for (int c8 = 0; c8 < 8; ++c8)
        ob[c8 * 16] = o[c8][r] * inv;
    }
  }
#undef STEP
#undef PV_ACC
#undef SOFTMAX_UPDATE
#undef QK_TILE
#undef STAGE_LOAD
#undef STAGE_WRITE
}

// ---------------------------------------------------------------------------
// Workspace layout (bytes):
//   0        : q_hash   [B,H,N] int   (256 KiB)
//   256 KiB  : k_hash                 (256 KiB)
//   512 KiB  : sort_idx               (256 KiB)
//   768 KiB  : keep[64] int
//   2 MiB    : Vt bf16 [B,H,D,N]      (16 MiB)
//   18 MiB   : Kb bf16 [B,H,N,D]      (16 MiB)   total 34 MiB
// ---------------------------------------------------------------------------
extern "C" void kernel_launch(void* const* d_in, const int* in_sizes, int n_in,
                              void* d_out, int out_size, void* d_ws, size_t ws_size,
                              hipStream_t stream) {
  const float* q = (const float*)d_in[0];
  const float* k = (const float*)d_in[1];
  const float* v = (const float*)d_in[2];
  const float* pd = (const float*)d_in[3];
  float* out = (float*)d_out;
  char* ws = (char*)d_ws;
  int* qh   = (int*)(ws + 0);
  int* kh   = (int*)(ws + (1u << 18));
  int* sidx = (int*)(ws + (2u << 18));
  int* keep = (int*)(ws + 3u * (1u << 18));
  unsigned short* Vt = (unsigned short*)(ws + (2u << 20));
  unsigned short* Kb = (unsigned short*)(ws + (18u << 20));

  prep_kernel<<<5120, 256, 0, stream>>>(q, k, v, pd, qh, kh, Vt, Kb);
  sortkeep_kernel<<<32, 512, 0, stream>>>(qh, kh, sidx, keep);
  flash_kernel<<<dim3(16, 32), 256, 0, stream>>>(q, Kb, Vt, sidx, keep, out);
}

// Round 4
// 344.109 us; speedup vs baseline: 1.0795x; 1.0639x over previous
//
#include <hip/hip_runtime.h>
#include <cstdint>

// Problem constants (B,N,H,D fixed by setup_inputs)
#define BB 2
#define NN 2048
#define HH 16
#define DD 128
#define BH 32   // BB*HH
#define NPROJ 7

typedef __bf16 bf16x8 __attribute__((ext_vector_type(8)));
typedef float f32x4 __attribute__((ext_vector_type(4)));

__device__ __forceinline__ unsigned short f2bf(float f) {
  unsigned int u = __float_as_uint(f);
  u += 0x7fff + ((u >> 16) & 1);   // RN-even
  return (unsigned short)(u >> 16);
}

__device__ __forceinline__ bf16x8 load_q8(const float* p) {
  float4 a = *(const float4*)p;
  float4 b = *(const float4*)(p + 4);
  unsigned short r[8] = {f2bf(a.x), f2bf(a.y), f2bf(a.z), f2bf(a.w),
                         f2bf(b.x), f2bf(b.y), f2bf(b.z), f2bf(b.w)};
  return *(bf16x8*)r;
}

// ---------------------------------------------------------------------------
// 1) Fused: LSH hash of q and k rows (blocks < 4096) + V bf16 transpose to
//    [B,H,D,N] (blocks >= 4096). Hash: 8 lanes per row, fp64 accumulation.
//    The k-hash path also emits K in bf16 [B,H,N,D] (Kb).  (unchanged)
// ---------------------------------------------------------------------------
__global__ void prep_kernel(const float* __restrict__ q, const float* __restrict__ k,
                            const float* __restrict__ v, const float* __restrict__ pd,
                            int* __restrict__ qh, int* __restrict__ kh,
                            unsigned short* __restrict__ Vt, unsigned short* __restrict__ Kb) {
  __shared__ __align__(16) char smem[64 * 132 * 2];  // union: spd (3.5K) / tile (16.5K)
  if (blockIdx.x < 4096) {
    float* spd = (float*)smem;
    for (int i = threadIdx.x; i < DD * NPROJ; i += 256) spd[i] = pd[i];
    __syncthreads();
    long long gid = (long long)blockIdx.x * 256 + threadIdx.x;
    int part = (int)(gid & 7);
    long long row = gid >> 3;
    const long long NR = (long long)BB * NN * HH;
    int isk = row >= NR;
    long long r = isk ? row - NR : row;            // flat [b][n][h]
    const float* src = (isk ? k : q) + r * DD + part * 16;
    double acc[NPROJ];
    for (int p = 0; p < NPROJ; ++p) acc[p] = 0.0;
    __align__(16) unsigned short kb16[16];
    for (int d = 0; d < 16; d += 4) {
      float4 x = *(const float4*)(src + d);
      if (isk) {
        kb16[d + 0] = f2bf(x.x); kb16[d + 1] = f2bf(x.y);
        kb16[d + 2] = f2bf(x.z); kb16[d + 3] = f2bf(x.w);
      }
      int dbase = part * 16 + d;
      for (int p = 0; p < NPROJ; ++p) {
        acc[p] += (double)x.x * (double)spd[(dbase + 0) * NPROJ + p]
                + (double)x.y * (double)spd[(dbase + 1) * NPROJ + p]
                + (double)x.z * (double)spd[(dbase + 2) * NPROJ + p]
                + (double)x.w * (double)spd[(dbase + 3) * NPROJ + p];
      }
    }
    int b_ = (int)(r / (NN * HH));
    int rem = (int)(r % (NN * HH));
    int n_ = rem / HH, h_ = rem % HH;
    if (isk) {
      unsigned short* dst = Kb + (((long long)(b_ * HH + h_) * NN + n_) << 7) + part * 16;
      *(uint4*)dst = *(const uint4*)&kb16[0];
      *(uint4*)(dst + 8) = *(const uint4*)&kb16[8];
    }
    for (int off = 1; off < 8; off <<= 1)
      for (int p = 0; p < NPROJ; ++p) acc[p] += __shfl_xor(acc[p], off);
    if (part == 0) {
      int bin = 0;
      for (int p = 0; p < NPROJ; ++p) bin |= ((int)(acc[p] > 0.0)) << p;
      int hsh = bin ^ (bin >> 1);                  // _unit_hamming == Gray code
      (isk ? kh : qh)[((long long)b_ * HH + h_) * NN + n_] = hsh;
    }
  } else {
    unsigned short (*tile)[132] = (unsigned short(*)[132])smem;
    int blk = blockIdx.x - 4096;
    int bh = blk >> 5;
    int n0 = (blk & 31) * 64;
    int b = bh >> 4, h = bh & 15;
    for (int it = 0; it < 8; ++it) {
      int cid = it * 256 + threadIdx.x;
      int r = cid >> 5, d4 = (cid & 31) * 4;
      float4 x = *(const float4*)(v + (((long long)(b * NN + n0 + r) * HH + h) << 7) + d4);
      *(ushort4*)&tile[r][d4] = make_ushort4(f2bf(x.x), f2bf(x.y), f2bf(x.z), f2bf(x.w));
    }
    __syncthreads();
    for (int it = 0; it < 8; ++it) {
      int cid = it * 256 + threadIdx.x;
      int d = cid >> 4, n4 = (cid & 15) * 4;
      ushort4 y = make_ushort4(tile[n4 + 0][d], tile[n4 + 1][d], tile[n4 + 2][d], tile[n4 + 3][d]);
      *(ushort4*)(Vt + ((long long)bh * DD + d) * NN + n0 + n4) = y;
    }
  }
}

// ---------------------------------------------------------------------------
// 2) Stable counting sort of q_hash per (b,h) + fused keep computation.
//    (unchanged)
// ---------------------------------------------------------------------------
__global__ void sortkeep_kernel(const int* __restrict__ qh, const int* __restrict__ kh,
                                int* __restrict__ sidx, int* __restrict__ keep) {
  __shared__ int sh[NN];
  __shared__ int cnt[4][128];
  __shared__ int cum[128];
  __shared__ int kflag[2];
  int bh = blockIdx.x;
  const int* src = qh + (long long)bh * NN;
  for (int i = threadIdx.x; i < NN; i += 512) sh[i] = src[i];
  if (threadIdx.x < 2) kflag[threadIdx.x] = 0;
  __syncthreads();
  int bin = threadIdx.x & 127, seg = threadIdx.x >> 7;
  int n0 = seg * (NN / 4);
  int c = 0;
  for (int n = n0; n < n0 + NN / 4; ++n) c += (sh[n] == bin);
  cnt[seg][bin] = c;
  __syncthreads();
  if (threadIdx.x == 0) {
    int run = 0;
    for (int t = 0; t < 128; ++t) {
      cum[t] = run;
      run += cnt[0][t] + cnt[1][t] + cnt[2][t] + cnt[3][t];
    }
  }
  __syncthreads();
  int pos = cum[bin];
  for (int s = 0; s < seg; ++s) pos += cnt[s][bin];
  int f0 = 0, f1 = 0;
  for (int n = n0; n < n0 + NN / 4; ++n)
    if (sh[n] == bin) {
      sidx[(long long)bh * NN + pos] = n;
      int match = (bin == kh[(long long)bh * NN + pos]);
      if (pos < 1024) f0 |= match; else f1 |= match;
      ++pos;
    }
  if (f0) atomicOr(&kflag[0], 1);
  if (f1) atomicOr(&kflag[1], 1);
  __syncthreads();
  if (threadIdx.x < 2) keep[bh * 2 + threadIdx.x] = kflag[threadIdx.x];
}

// ---------------------------------------------------------------------------
// 3) Flash attention over sorted Q.
//    ROUND 4: occupancy fix. Two-phase pairing dropped -> ONE 64-row q-tile
//    per block, grid (bh=32, tile=32) = 1024 blocks launched heavy-first
//    (qt = 31 - blockIdx.y; bh fastest-varying) so dynamic scheduling packs
//    the causal triangle. Single-buffered K/V in LDS (45056 B -> 3 blocks/CU,
//    12 waves/CU, +50% latency hiding vs rounds 0-3's hard 8-wave cap); the
//    in-flight kreg/vreg register prefetch (async-split staging) is the
//    second buffer. s_setprio(1) around MFMA clusters (independent blocks,
//    attn-positive per m191). Per-wave math identical to round 1.
// ---------------------------------------------------------------------------
__global__ __launch_bounds__(256, 3)
void flash_kernel(const float* __restrict__ q, const unsigned short* __restrict__ Kb,
                  const unsigned short* __restrict__ Vt, const int* __restrict__ sidx,
                  const int* __restrict__ keep, float* __restrict__ out) {
  __shared__ __align__(16) unsigned short Kt[64 * 136];   // keys x d (+8 pad)
  __shared__ __align__(16) unsigned short Vs[128 * 72];   // d x keys (+8 pad)
  __shared__ __align__(16) unsigned short Pb[4][16 * 72]; // per-wave q x keys

  int bh = blockIdx.x;              // 0..31 (fastest -> heavy tiles spread first)
  int qt = 31 - (int)blockIdx.y;    // 31..0, heavy tiles launch first
  int b = bh >> 4, h = bh & 15;
  int tid = threadIdx.x;
  int w = tid >> 6, lane = tid & 63;
  int l16 = lane & 15, qd = lane >> 4;

  const unsigned short* Kh = Kb + (long long)bh * NN * DD;
  const unsigned short* Vb = Vt + (long long)bh * DD * NN;
  const float scale = 0.088388347648318447f;  // 128^-0.5

  // staging geometry: K tile 64x128 bf16 (16KB), V tile 128x64 bf16 (16KB)
  const int ksr = tid >> 4;          // K row base (+ it*16)
  const int ksc = (tid & 15) * 8;    // K col (ushort units)
  const int vsr = tid >> 3;          // V row base (+ it*32)
  const int vsc = (tid & 7) * 8;     // V col (ushort units)

  uint4 kreg[4], vreg[4];

#define STAGE_LOAD(K0, KP)                                                            \
  {                                                                                   \
    if (KP) {                                                                         \
      _Pragma("unroll")                                                               \
      for (int it = 0; it < 4; ++it)                                                  \
        kreg[it] = *(const uint4*)(Kh + (long long)((K0) + it * 16 + ksr) * DD + ksc);\
    } else {                                                                          \
      _Pragma("unroll")                                                               \
      for (int it = 0; it < 4; ++it) kreg[it] = make_uint4(0, 0, 0, 0);               \
    }                                                                                 \
    _Pragma("unroll")                                                                 \
    for (int it = 0; it < 4; ++it)                                                    \
      vreg[it] = *(const uint4*)(Vb + (long long)(it * 32 + vsr) * NN + (K0) + vsc);  \
  }

#define STAGE_WRITE()                                                                 \
  {                                                                                   \
    _Pragma("unroll")                                                                 \
    for (int it = 0; it < 4; ++it)                                                    \
      *(uint4*)&Kt[(it * 16 + ksr) * 136 + ksc] = kreg[it];                           \
    _Pragma("unroll")                                                                 \
    for (int it = 0; it < 4; ++it)                                                    \
      *(uint4*)&Vs[(it * 32 + vsr) * 72 + vsc] = vreg[it];                            \
  }

  int qrow = qt * 64 + w * 16 + l16;

  // Q fragments, gathered from fp32 q via sidx (once per block)
  bf16x8 qf[4];
  {
    int nq = sidx[bh * NN + qrow];
    const float* p0 = q + (((long long)(b * NN + nq) * HH + h) << 7) + qd * 8;
#pragma unroll
    for (int c = 0; c < 4; ++c) qf[c] = load_q8(p0 + c * 32);
  }
  f32x4 o[8];
#pragma unroll
  for (int i = 0; i < 8; ++i) o[i] = (f32x4){0.f, 0.f, 0.f, 0.f};
  float m = -__builtin_inff(), l = 0.f;

  // prologue: stage tile 0 (fresh LDS, no prior readers)
  STAGE_LOAD(0, keep[h * 4]);
  STAGE_WRITE();
  __syncthreads();

  for (int kb = 0; kb <= qt; ++kb) {
    // issue next tile's global loads BEFORE compute (latency hides here)
    if (kb < qt) STAGE_LOAD((kb + 1) * 64, keep[h * 4 + ((kb + 1) >> 3)]);

    int k0 = kb * 64;

    // --- S^T = K * Q^T (K fragments from LDS) ---
    float s[16];
    __builtin_amdgcn_s_setprio(1);
#pragma unroll
    for (int t = 0; t < 4; ++t) {
      f32x4 a1 = (f32x4){0.f, 0.f, 0.f, 0.f};
#pragma unroll
      for (int c = 0; c < 4; ++c) {
        bf16x8 kf = *(const bf16x8*)&Kt[(t * 16 + l16) * 136 + c * 32 + qd * 8];
        a1 = __builtin_amdgcn_mfma_f32_16x16x32_bf16(kf, qf[c], a1, 0, 0, 0);
      }
      if (kb == qt) {              // causal mask only on the diagonal tile
#pragma unroll
        for (int r = 0; r < 4; ++r) {
          int keyg = k0 + t * 16 + qd * 4 + r;
          s[t * 4 + r] = (keyg > qrow) ? -__builtin_inff() : a1[r] * scale;
        }
      } else {
#pragma unroll
        for (int r = 0; r < 4; ++r) s[t * 4 + r] = a1[r] * scale;
      }
    }
    __builtin_amdgcn_s_setprio(0);

    // --- online softmax (stats per q = lane&15, replicated across quads) ---
    {
      float x0 = fmaxf(fmaxf(s[0], s[1]), fmaxf(s[2], s[3]));
      float x1 = fmaxf(fmaxf(s[4], s[5]), fmaxf(s[6], s[7]));
      float x2 = fmaxf(fmaxf(s[8], s[9]), fmaxf(s[10], s[11]));
      float x3 = fmaxf(fmaxf(s[12], s[13]), fmaxf(s[14], s[15]));
      float mloc = fmaxf(fmaxf(x0, x1), fmaxf(x2, x3));
      mloc = fmaxf(mloc, __shfl_xor(mloc, 16));
      mloc = fmaxf(mloc, __shfl_xor(mloc, 32));
      if (__any(mloc > m)) {       // alpha==1 exactly when skipped
        float mnew = fmaxf(m, mloc);
        float alpha = __expf(m - mnew);
        float aO[4];
#pragma unroll
        for (int r = 0; r < 4; ++r) aO[r] = __shfl(alpha, qd * 4 + r);
#pragma unroll
        for (int c8 = 0; c8 < 8; ++c8)
#pragma unroll
          for (int r = 0; r < 4; ++r) o[c8][r] *= aO[r];
        l *= alpha;
        m = mnew;
      }
      float psum = 0.f;
#pragma unroll
      for (int t = 0; t < 4; ++t) {
        float p0 = __expf(s[t * 4 + 0] - m);
        float p1 = __expf(s[t * 4 + 1] - m);
        float p2 = __expf(s[t * 4 + 2] - m);
        float p3 = __expf(s[t * 4 + 3] - m);
        psum += (p0 + p1) + (p2 + p3);
        *(ushort4*)&Pb[w][l16 * 72 + t * 16 + qd * 4] =
            make_ushort4(f2bf(p0), f2bf(p1), f2bf(p2), f2bf(p3));
      }
      psum += __shfl_xor(psum, 16);
      psum += __shfl_xor(psum, 32);
      l += psum;
    }

    // --- O += P * V  (V fragments from LDS) ---
    __builtin_amdgcn_s_setprio(1);
#pragma unroll
    for (int g = 0; g < 2; ++g) {
      bf16x8 pf = *(const bf16x8*)&Pb[w][l16 * 72 + g * 32 + qd * 8];
#pragma unroll
      for (int c8 = 0; c8 < 8; ++c8) {
        bf16x8 vf = *(const bf16x8*)&Vs[(c8 * 16 + l16) * 72 + g * 32 + qd * 8];
        o[c8] = __builtin_amdgcn_mfma_f32_16x16x32_bf16(pf, vf, o[c8], 0, 0, 0);
      }
    }
    __builtin_amdgcn_s_setprio(0);

    // single LDS buffer: wait for all readers, then overwrite with next tile
    if (kb < qt) {
      __syncthreads();
      STAGE_WRITE();
      __syncthreads();
    }
  }

  // --- epilogue: normalize and scatter-unsort (no LDS access) ---
  float lO[4];
  int nO[4];
#pragma unroll
  for (int r = 0; r < 4; ++r) {
    lO[r] = __shfl(l, qd * 4 + r);
    nO[r] = sidx[(long long)bh * NN + qt * 64 + w * 16 + qd * 4 + r];
  }
#pragma unroll
  for (int r = 0; r < 4; ++r) {
    float inv = 1.f / lO[r];
    float* ob = out + (((long long)(b * NN + nO[r]) * HH + h) << 7) + l16;
#pragma unroll
    for (int c8 = 0; c8 < 8; ++c8)
      ob[c8 * 16] = o[c8][r] * inv;
  }
#undef STAGE_LOAD
#undef STAGE_WRITE
}

// ---------------------------------------------------------------------------
// Workspace layout (bytes):
//   0        : q_hash   [B,H,N] int   (256 KiB)
//   256 KiB  : k_hash                 (256 KiB)
//   512 KiB  : sort_idx               (256 KiB)
//   768 KiB  : keep[64] int
//   2 MiB    : Vt bf16 [B,H,D,N]      (16 MiB)
//   18 MiB   : Kb bf16 [B,H,N,D]      (16 MiB)   total 34 MiB
// ---------------------------------------------------------------------------
extern "C" void kernel_launch(void* const* d_in, const int* in_sizes, int n_in,
                              void* d_out, int out_size, void* d_ws, size_t ws_size,
                              hipStream_t stream) {
  const float* q = (const float*)d_in[0];
  const float* k = (const float*)d_in[1];
  const float* v = (const float*)d_in[2];
  const float* pd = (const float*)d_in[3];
  float* out = (float*)d_out;
  char* ws = (char*)d_ws;
  int* qh   = (int*)(ws + 0);
  int* kh   = (int*)(ws + (1u << 18));
  int* sidx = (int*)(ws + (2u << 18));
  int* keep = (int*)(ws + 3u * (1u << 18));
  unsigned short* Vt = (unsigned short*)(ws + (2u << 20));
  unsigned short* Kb = (unsigned short*)(ws + (18u << 20));

  prep_kernel<<<5120, 256, 0, stream>>>(q, k, v, pd, qh, kh, Vt, Kb);
  sortkeep_kernel<<<32, 512, 0, stream>>>(qh, kh, sidx, keep);
  flash_kernel<<<dim3(32, 32), 256, 0, stream>>>(q, Kb, Vt, sidx, keep, out);
}

// Round 5
// 339.727 us; speedup vs baseline: 1.0934x; 1.0129x over previous
//
#include <hip/hip_runtime.h>
#include <cstdint>

// Problem constants (B,N,H,D fixed by setup_inputs)
#define BB 2
#define NN 2048
#define HH 16
#define DD 128
#define BH 32   // BB*HH
#define NPROJ 7

typedef __bf16 bf16x8 __attribute__((ext_vector_type(8)));
typedef float f32x4 __attribute__((ext_vector_type(4)));
typedef short short4v __attribute__((ext_vector_type(4)));
typedef unsigned int uint2v __attribute__((ext_vector_type(2)));

__device__ __forceinline__ unsigned short f2bf(float f) {
  unsigned int u = __float_as_uint(f);
  u += 0x7fff + ((u >> 16) & 1);   // RN-even
  return (unsigned short)(u >> 16);
}

__device__ __forceinline__ bf16x8 load_q8(const float* p) {
  float4 a = *(const float4*)p;
  float4 b = *(const float4*)(p + 4);
  unsigned short r[8] = {f2bf(a.x), f2bf(a.y), f2bf(a.z), f2bf(a.w),
                         f2bf(b.x), f2bf(b.y), f2bf(b.z), f2bf(b.w)};
  return *(bf16x8*)r;
}

// packed f32x2 -> bf16x2 (RNE), single instruction
__device__ __forceinline__ unsigned cvt_pk_bf16(float lo, float hi) {
  unsigned r;
  asm("v_cvt_pk_bf16_f32 %0, %1, %2" : "=v"(r) : "v"(lo), "v"(hi));
  return r;
}

#if __has_builtin(__builtin_amdgcn_exp2f)
#define EXP2(x) __builtin_amdgcn_exp2f(x)
#else
#define EXP2(x) exp2f(x)
#endif

// K=16 bf16 MFMA: lane holds A[l&15][(l>>4)*4+j] / B[(l>>4)*4+j][l&15]
__device__ __forceinline__ f32x4 mfma16(short4v a, short4v b, f32x4 c) {
#if __has_builtin(__builtin_amdgcn_mfma_f32_16x16x16bf16_1k)
  return __builtin_amdgcn_mfma_f32_16x16x16bf16_1k(a, b, c, 0, 0, 0);
#else
  asm("v_mfma_f32_16x16x16_bf16 %0, %1, %2, %0" : "+v"(c) : "v"(a), "v"(b));
  return c;
#endif
}

// ---------------------------------------------------------------------------
// 1) Fused: LSH hash of q and k rows (blocks < 4096) + V bf16 transpose to
//    [B,H,D,N] (blocks >= 4096). Hash: 8 lanes per row, fp64 accumulation.
//    The k-hash path also emits K in bf16 [B,H,N,D] (Kb).  (unchanged)
// ---------------------------------------------------------------------------
__global__ void prep_kernel(const float* __restrict__ q, const float* __restrict__ k,
                            const float* __restrict__ v, const float* __restrict__ pd,
                            int* __restrict__ qh, int* __restrict__ kh,
                            unsigned short* __restrict__ Vt, unsigned short* __restrict__ Kb) {
  __shared__ __align__(16) char smem[64 * 132 * 2];  // union: spd (3.5K) / tile (16.5K)
  if (blockIdx.x < 4096) {
    float* spd = (float*)smem;
    for (int i = threadIdx.x; i < DD * NPROJ; i += 256) spd[i] = pd[i];
    __syncthreads();
    long long gid = (long long)blockIdx.x * 256 + threadIdx.x;
    int part = (int)(gid & 7);
    long long row = gid >> 3;
    const long long NR = (long long)BB * NN * HH;
    int isk = row >= NR;
    long long r = isk ? row - NR : row;            // flat [b][n][h]
    const float* src = (isk ? k : q) + r * DD + part * 16;
    double acc[NPROJ];
    for (int p = 0; p < NPROJ; ++p) acc[p] = 0.0;
    __align__(16) unsigned short kb16[16];
    for (int d = 0; d < 16; d += 4) {
      float4 x = *(const float4*)(src + d);
      if (isk) {
        kb16[d + 0] = f2bf(x.x); kb16[d + 1] = f2bf(x.y);
        kb16[d + 2] = f2bf(x.z); kb16[d + 3] = f2bf(x.w);
      }
      int dbase = part * 16 + d;
      for (int p = 0; p < NPROJ; ++p) {
        acc[p] += (double)x.x * (double)spd[(dbase + 0) * NPROJ + p]
                + (double)x.y * (double)spd[(dbase + 1) * NPROJ + p]
                + (double)x.z * (double)spd[(dbase + 2) * NPROJ + p]
                + (double)x.w * (double)spd[(dbase + 3) * NPROJ + p];
      }
    }
    int b_ = (int)(r / (NN * HH));
    int rem = (int)(r % (NN * HH));
    int n_ = rem / HH, h_ = rem % HH;
    if (isk) {
      unsigned short* dst = Kb + (((long long)(b_ * HH + h_) * NN + n_) << 7) + part * 16;
      *(uint4*)dst = *(const uint4*)&kb16[0];
      *(uint4*)(dst + 8) = *(const uint4*)&kb16[8];
    }
    for (int off = 1; off < 8; off <<= 1)
      for (int p = 0; p < NPROJ; ++p) acc[p] += __shfl_xor(acc[p], off);
    if (part == 0) {
      int bin = 0;
      for (int p = 0; p < NPROJ; ++p) bin |= ((int)(acc[p] > 0.0)) << p;
      int hsh = bin ^ (bin >> 1);                  // _unit_hamming == Gray code
      (isk ? kh : qh)[((long long)b_ * HH + h_) * NN + n_] = hsh;
    }
  } else {
    unsigned short (*tile)[132] = (unsigned short(*)[132])smem;
    int blk = blockIdx.x - 4096;
    int bh = blk >> 5;
    int n0 = (blk & 31) * 64;
    int b = bh >> 4, h = bh & 15;
    for (int it = 0; it < 8; ++it) {
      int cid = it * 256 + threadIdx.x;
      int r = cid >> 5, d4 = (cid & 31) * 4;
      float4 x = *(const float4*)(v + (((long long)(b * NN + n0 + r) * HH + h) << 7) + d4);
      *(ushort4*)&tile[r][d4] = make_ushort4(f2bf(x.x), f2bf(x.y), f2bf(x.z), f2bf(x.w));
    }
    __syncthreads();
    for (int it = 0; it < 8; ++it) {
      int cid = it * 256 + threadIdx.x;
      int d = cid >> 4, n4 = (cid & 15) * 4;
      ushort4 y = make_ushort4(tile[n4 + 0][d], tile[n4 + 1][d], tile[n4 + 2][d], tile[n4 + 3][d]);
      *(ushort4*)(Vt + ((long long)bh * DD + d) * NN + n0 + n4) = y;
    }
  }
}

// ---------------------------------------------------------------------------
// 2) Stable counting sort of q_hash per (b,h) + fused keep computation.
//    ROUND 5: 1024 threads (8 segments x 128 bins) -> serial scans halve
//    from 512 to 256 elements per thread.
// ---------------------------------------------------------------------------
__global__ void sortkeep_kernel(const int* __restrict__ qh, const int* __restrict__ kh,
                                int* __restrict__ sidx, int* __restrict__ keep) {
  __shared__ int sh[NN];
  __shared__ int cnt[8][128];
  __shared__ int cum[128];
  __shared__ int kflag[2];
  int bh = blockIdx.x;
  const int* src = qh + (long long)bh * NN;
  for (int i = threadIdx.x; i < NN; i += 1024) sh[i] = src[i];
  if (threadIdx.x < 2) kflag[threadIdx.x] = 0;
  __syncthreads();
  int bin = threadIdx.x & 127, seg = threadIdx.x >> 7;   // seg 0..7
  int n0 = seg * (NN / 8);
  int c = 0;
  for (int n = n0; n < n0 + NN / 8; ++n) c += (sh[n] == bin);
  cnt[seg][bin] = c;
  __syncthreads();
  if (threadIdx.x == 0) {
    int run = 0;
    for (int t = 0; t < 128; ++t) {
      cum[t] = run;
      run += cnt[0][t] + cnt[1][t] + cnt[2][t] + cnt[3][t]
           + cnt[4][t] + cnt[5][t] + cnt[6][t] + cnt[7][t];
    }
  }
  __syncthreads();
  int pos = cum[bin];
  for (int s = 0; s < seg; ++s) pos += cnt[s][bin];
  int f0 = 0, f1 = 0;
  for (int n = n0; n < n0 + NN / 8; ++n)
    if (sh[n] == bin) {
      sidx[(long long)bh * NN + pos] = n;
      int match = (bin == kh[(long long)bh * NN + pos]);
      if (pos < 1024) f0 |= match; else f1 |= match;
      ++pos;
    }
  if (f0) atomicOr(&kflag[0], 1);
  if (f1) atomicOr(&kflag[1], 1);
  __syncthreads();
  if (threadIdx.x < 2) keep[bh * 2 + threadIdx.x] = kflag[threadIdx.x];
}

// ---------------------------------------------------------------------------
// 3) Flash attention over sorted Q.
//    ROUND 5 (on top of R4's 1024-block heavy-first grid):
//      - PV via K=16 MFMAs with P kept IN REGISTERS: after swapped QK, lane
//        (l16,qd) holds P[q=l16][key=t*16+qd*4+r] == the A-fragment layout of
//        mfma_f32_16x16x16_bf16. Pb LDS buffer deleted (no f2bf->ds_write->
//        ds_read chain); P converted via v_cvt_pk_bf16_f32 (8 instrs).
//      - exp2 folding: m tracked in raw-S domain, p = exp2(s*c - m*c) with
//        c = scale*log2(e); saves ~32 VALU/iter. Identical math.
//      - LDS 35840 B -> 4 blocks/CU (16 waves) at __launch_bounds__(256,4).
// ---------------------------------------------------------------------------
__global__ __launch_bounds__(256, 4)
void flash_kernel(const float* __restrict__ q, const unsigned short* __restrict__ Kb,
                  const unsigned short* __restrict__ Vt, const int* __restrict__ sidx,
                  const int* __restrict__ keep, float* __restrict__ out) {
  __shared__ __align__(16) unsigned short Kt[64 * 136];   // keys x d (+8 pad)
  __shared__ __align__(16) unsigned short Vs[128 * 72];   // d x keys (+8 pad)

  int bh = blockIdx.x;              // 0..31 (fastest -> heavy tiles spread first)
  int qt = 31 - (int)blockIdx.y;    // 31..0, heavy tiles launch first
  int b = bh >> 4, h = bh & 15;
  int tid = threadIdx.x;
  int w = tid >> 6, lane = tid & 63;
  int l16 = lane & 15, qd = lane >> 4;
  (void)w;

  const unsigned short* Kh = Kb + (long long)bh * NN * DD;
  const unsigned short* Vb = Vt + (long long)bh * DD * NN;
  const float CEXP = 0.1275174316582815f;  // 128^-0.5 * log2(e)

  // staging geometry: K tile 64x128 bf16 (16KB), V tile 128x64 bf16 (16KB)
  const int ksr = tid >> 4;          // K row base (+ it*16)
  const int ksc = (tid & 15) * 8;    // K col (ushort units)
  const int vsr = tid >> 3;          // V row base (+ it*32)
  const int vsc = (tid & 7) * 8;     // V col (ushort units)

  uint4 kreg[4], vreg[4];

#define STAGE_LOAD(K0, KP)                                                            \
  {                                                                                   \
    if (KP) {                                                                         \
      _Pragma("unroll")                                                               \
      for (int it = 0; it < 4; ++it)                                                  \
        kreg[it] = *(const uint4*)(Kh + (long long)((K0) + it * 16 + ksr) * DD + ksc);\
    } else {                                                                          \
      _Pragma("unroll")                                                               \
      for (int it = 0; it < 4; ++it) kreg[it] = make_uint4(0, 0, 0, 0);               \
    }                                                                                 \
    _Pragma("unroll")                                                                 \
    for (int it = 0; it < 4; ++it)                                                    \
      vreg[it] = *(const uint4*)(Vb + (long long)(it * 32 + vsr) * NN + (K0) + vsc);  \
  }

#define STAGE_WRITE()                                                                 \
  {                                                                                   \
    _Pragma("unroll")                                                                 \
    for (int it = 0; it < 4; ++it)                                                    \
      *(uint4*)&Kt[(it * 16 + ksr) * 136 + ksc] = kreg[it];                           \
    _Pragma("unroll")                                                                 \
    for (int it = 0; it < 4; ++it)                                                    \
      *(uint4*)&Vs[(it * 32 + vsr) * 72 + vsc] = vreg[it];                            \
  }

  int qrow = qt * 64 + w * 16 + l16;

  // Q fragments, gathered from fp32 q via sidx (once per block)
  bf16x8 qf[4];
  {
    int nq = sidx[bh * NN + qrow];
    const float* p0 = q + (((long long)(b * NN + nq) * HH + h) << 7) + qd * 8;
#pragma unroll
    for (int c = 0; c < 4; ++c) qf[c] = load_q8(p0 + c * 32);
  }
  f32x4 o[8];
#pragma unroll
  for (int i = 0; i < 8; ++i) o[i] = (f32x4){0.f, 0.f, 0.f, 0.f};
  float m = -__builtin_inff(), l = 0.f;

  // prologue: stage tile 0 (fresh LDS, no prior readers)
  STAGE_LOAD(0, keep[h * 4]);
  STAGE_WRITE();
  __syncthreads();

  for (int kb = 0; kb <= qt; ++kb) {
    // issue next tile's global loads BEFORE compute (latency hides here)
    if (kb < qt) STAGE_LOAD((kb + 1) * 64, keep[h * 4 + ((kb + 1) >> 3)]);

    int k0 = kb * 64;

    // --- S^T = K * Q^T (K fragments from LDS), RAW scores (no scale) ---
    float s[16];
    __builtin_amdgcn_s_setprio(1);
#pragma unroll
    for (int t = 0; t < 4; ++t) {
      f32x4 a1 = (f32x4){0.f, 0.f, 0.f, 0.f};
#pragma unroll
      for (int c = 0; c < 4; ++c) {
        bf16x8 kf = *(const bf16x8*)&Kt[(t * 16 + l16) * 136 + c * 32 + qd * 8];
        a1 = __builtin_amdgcn_mfma_f32_16x16x32_bf16(kf, qf[c], a1, 0, 0, 0);
      }
      if (kb == qt) {              // causal mask only on the diagonal tile
#pragma unroll
        for (int r = 0; r < 4; ++r) {
          int keyg = k0 + t * 16 + qd * 4 + r;
          s[t * 4 + r] = (keyg > qrow) ? -__builtin_inff() : a1[r];
        }
      } else {
#pragma unroll
        for (int r = 0; r < 4; ++r) s[t * 4 + r] = a1[r];
      }
    }
    __builtin_amdgcn_s_setprio(0);

    // --- online softmax in raw-S domain; P built in registers (bf16x4) ---
    short4v pf[4];
    {
      float x0 = fmaxf(fmaxf(s[0], s[1]), fmaxf(s[2], s[3]));
      float x1 = fmaxf(fmaxf(s[4], s[5]), fmaxf(s[6], s[7]));
      float x2 = fmaxf(fmaxf(s[8], s[9]), fmaxf(s[10], s[11]));
      float x3 = fmaxf(fmaxf(s[12], s[13]), fmaxf(s[14], s[15]));
      float mloc = fmaxf(fmaxf(x0, x1), fmaxf(x2, x3));
      mloc = fmaxf(mloc, __shfl_xor(mloc, 16));
      mloc = fmaxf(mloc, __shfl_xor(mloc, 32));
      if (__any(mloc > m)) {       // alpha==1 exactly when skipped
        float mnew = fmaxf(m, mloc);
        float alpha = EXP2((m - mnew) * CEXP);
        float aO[4];
#pragma unroll
        for (int r = 0; r < 4; ++r) aO[r] = __shfl(alpha, qd * 4 + r);
#pragma unroll
        for (int c8 = 0; c8 < 8; ++c8)
#pragma unroll
          for (int r = 0; r < 4; ++r) o[c8][r] *= aO[r];
        l *= alpha;
        m = mnew;
      }
      float mc = m * CEXP;
      float psum = 0.f;
#pragma unroll
      for (int t = 0; t < 4; ++t) {
        float p0 = EXP2(__builtin_fmaf(s[t * 4 + 0], CEXP, -mc));
        float p1 = EXP2(__builtin_fmaf(s[t * 4 + 1], CEXP, -mc));
        float p2 = EXP2(__builtin_fmaf(s[t * 4 + 2], CEXP, -mc));
        float p3 = EXP2(__builtin_fmaf(s[t * 4 + 3], CEXP, -mc));
        psum += (p0 + p1) + (p2 + p3);
        uint2v pk = {cvt_pk_bf16(p0, p1), cvt_pk_bf16(p2, p3)};
        pf[t] = __builtin_bit_cast(short4v, pk);
      }
      psum += __shfl_xor(psum, 16);
      psum += __shfl_xor(psum, 32);
      l += psum;
    }

    // --- O += P * V  (P in registers; V b64 fragments; K=16 MFMAs) ---
    __builtin_amdgcn_s_setprio(1);
#pragma unroll
    for (int t = 0; t < 4; ++t) {
#pragma unroll
      for (int c8 = 0; c8 < 8; ++c8) {
        short4v vf = *(const short4v*)&Vs[(c8 * 16 + l16) * 72 + t * 16 + qd * 4];
        o[c8] = mfma16(pf[t], vf, o[c8]);
      }
    }
    __builtin_amdgcn_s_setprio(0);

    // single LDS buffer: wait for all readers, then overwrite with next tile
    if (kb < qt) {
      __syncthreads();
      STAGE_WRITE();
      __syncthreads();
    }
  }

  // --- epilogue: normalize and scatter-unsort (no LDS access) ---
  float lO[4];
  int nO[4];
#pragma unroll
  for (int r = 0; r < 4; ++r) {
    lO[r] = __shfl(l, qd * 4 + r);
    nO[r] = sidx[(long long)bh * NN + qt * 64 + w * 16 + qd * 4 + r];
  }
#pragma unroll
  for (int r = 0; r < 4; ++r) {
    float inv = 1.f / lO[r];
    float* ob = out + (((long long)(b * NN + nO[r]) * HH + h) << 7) + l16;
#pragma unroll
    for (int c8 = 0; c8 < 8; ++c8)
      ob[c8 * 16] = o[c8][r] * inv;
  }
#undef STAGE_LOAD
#undef STAGE_WRITE
}

// ---------------------------------------------------------------------------
// Workspace layout (bytes):
//   0        : q_hash   [B,H,N] int   (256 KiB)
//   256 KiB  : k_hash                 (256 KiB)
//   512 KiB  : sort_idx               (256 KiB)
//   768 KiB  : keep[64] int
//   2 MiB    : Vt bf16 [B,H,D,N]      (16 MiB)
//   18 MiB   : Kb bf16 [B,H,N,D]      (16 MiB)   total 34 MiB
// ---------------------------------------------------------------------------
extern "C" void kernel_launch(void* const* d_in, const int* in_sizes, int n_in,
                              void* d_out, int out_size, void* d_ws, size_t ws_size,
                              hipStream_t stream) {
  const float* q = (const float*)d_in[0];
  const float* k = (const float*)d_in[1];
  const float* v = (const float*)d_in[2];
  const float* pd = (const float*)d_in[3];
  float* out = (float*)d_out;
  char* ws = (char*)d_ws;
  int* qh   = (int*)(ws + 0);
  int* kh   = (int*)(ws + (1u << 18));
  int* sidx = (int*)(ws + (2u << 18));
  int* keep = (int*)(ws + 3u * (1u << 18));
  unsigned short* Vt = (unsigned short*)(ws + (2u << 20));
  unsigned short* Kb = (unsigned short*)(ws + (18u << 20));

  prep_kernel<<<5120, 256, 0, stream>>>(q, k, v, pd, qh, kh, Vt, Kb);
  sortkeep_kernel<<<32, 1024, 0, stream>>>(qh, kh, sidx, keep);
  flash_kernel<<<dim3(32, 32), 256, 0, stream>>>(q, Kb, Vt, sidx, keep, out);
}